// Round 1
// baseline (59.684 us; speedup 1.0000x reference)
//
#include <hip/hip_runtime.h>
#include <math.h>

#define NCAMS 6
#define CCH   32
#define YY    8
#define XX    256
#define ZZ    256
#define NVOX  (YY*XX*ZZ)        // 524288
#define IMG_H 224
#define IMG_W 400
#define FXV   56
#define FZV   100

__global__ __launch_bounds__(256) void mvmap_main(
    const float* __restrict__ img_feats,    // [6,32,56,100]
    const float* __restrict__ variances,    // [6,1,224,400]
    const float* __restrict__ render_depth, // [6,1,224,400]
    const float* __restrict__ coords,       // [1,524288,3]  (px, pz, h)
    const float* __restrict__ Ps,           // [6,4,4] cam2world
    const float* __restrict__ Ks,           // [6,3,3]
    float* __restrict__ out)                // out_feats | var_info | depth | nerf_depth
{
    __shared__ float sW2C[NCAMS][12];   // world->cam, rows of [R^-1 | -R^-1 t]
    __shared__ float sK[NCAMS][9];

    if (threadIdx.x < NCAMS) {
        int b = threadIdx.x;
        const float* P = Ps + b * 16;
        float r00=P[0], r01=P[1], r02=P[2],  tx=P[3];
        float r10=P[4], r11=P[5], r12=P[6],  ty=P[7];
        float r20=P[8], r21=P[9], r22=P[10], tz=P[11];
        float det = r00*(r11*r22 - r12*r21)
                  - r01*(r10*r22 - r12*r20)
                  + r02*(r10*r21 - r11*r20);
        float id = 1.0f / det;
        float i00 =  (r11*r22 - r12*r21) * id;
        float i01 = -(r01*r22 - r02*r21) * id;
        float i02 =  (r01*r12 - r02*r11) * id;
        float i10 = -(r10*r22 - r12*r20) * id;
        float i11 =  (r00*r22 - r02*r20) * id;
        float i12 = -(r00*r12 - r02*r10) * id;
        float i20 =  (r10*r21 - r11*r20) * id;
        float i21 = -(r00*r21 - r01*r20) * id;
        float i22 =  (r00*r11 - r01*r10) * id;
        sW2C[b][0]=i00; sW2C[b][1]=i01; sW2C[b][2] =i02; sW2C[b][3] =-(i00*tx + i01*ty + i02*tz);
        sW2C[b][4]=i10; sW2C[b][5]=i11; sW2C[b][6] =i12; sW2C[b][7] =-(i10*tx + i11*ty + i12*tz);
        sW2C[b][8]=i20; sW2C[b][9]=i21; sW2C[b][10]=i22; sW2C[b][11]=-(i20*tx + i21*ty + i22*tz);
        #pragma unroll
        for (int j = 0; j < 9; j++) sK[b][j] = Ks[b*9 + j];
    }
    __syncthreads();

    int n = blockIdx.x * blockDim.x + threadIdx.x;
    if (n >= NVOX) return;

    float px = coords[3*n + 0];
    float pz = coords[3*n + 1];
    float ph = coords[3*n + 2];

    float fsum[CCH];
    #pragma unroll
    for (int c = 0; c < CCH; c++) fsum[c] = 0.0f;
    float wsum = 0.0f, vsum = 0.0f, ndsum = 0.0f, zsum = 0.0f;

    for (int b = 0; b < NCAMS; b++) {
        // world -> cam -> pixel
        float cx = sW2C[b][0]*px + sW2C[b][1]*pz + sW2C[b][2] *ph + sW2C[b][3];
        float cy = sW2C[b][4]*px + sW2C[b][5]*pz + sW2C[b][6] *ph + sW2C[b][7];
        float cz = sW2C[b][8]*px + sW2C[b][9]*pz + sW2C[b][10]*ph + sW2C[b][11];
        float u0 = sK[b][0]*cx + sK[b][1]*cy + sK[b][2]*cz;
        float v0 = sK[b][3]*cx + sK[b][4]*cy + sK[b][5]*cz;
        float zc = sK[b][6]*cx + sK[b][7]*cy + sK[b][8]*cz;
        float zsafe = (fabsf(zc) < 1e-6f) ? 1e-6f : zc;
        float u = u0 / zsafe;
        float v = v0 / zsafe;
        bool mask = (zc > 1e-3f) && (u >= 0.0f) && (u < (float)IMG_W)
                                 && (v >= 0.0f) && (v < (float)IMG_H);
        if (!mask) continue;

        wsum += 1.0f;
        zsum += zc;

        // ---- feature bilinear on swapped [ZV=100 (h), XV=56 (w)] grid ----
        // x (width, XV) from v; y (height, ZV) from u; align_corners=False
        {
            float xf = v * 0.25f - 0.5f;      // (gx+1)*28 - 0.5
            float yf = u * 0.25f - 0.5f;      // (gy+1)*50 - 0.5
            float x0f = floorf(xf), y0f = floorf(yf);
            float wx = xf - x0f, wy = yf - y0f;
            int x0 = (int)x0f, y0 = (int)y0f;
            float vx0 = (x0   >= 0 && x0   < FXV) ? 1.0f : 0.0f;
            float vx1 = (x0+1 >= 0 && x0+1 < FXV) ? 1.0f : 0.0f;
            float vy0 = (y0   >= 0 && y0   < FZV) ? 1.0f : 0.0f;
            float vy1 = (y0+1 >= 0 && y0+1 < FZV) ? 1.0f : 0.0f;
            float w00 = (1.0f-wx)*(1.0f-wy)*vx0*vy0;
            float w10 = wx*(1.0f-wy)*vx1*vy0;
            float w01 = (1.0f-wx)*wy*vx0*vy1;
            float w11 = wx*wy*vx1*vy1;
            int xi0 = min(max(x0,   0), FXV-1), xi1 = min(max(x0+1, 0), FXV-1);
            int yi0 = min(max(y0,   0), FZV-1), yi1 = min(max(y0+1, 0), FZV-1);
            // img_feats[b,c,xi,yi] -> offset c*5600 + xi*100 + yi
            int o00 = xi0*FZV + yi0, o01 = xi0*FZV + yi1;
            int o10 = xi1*FZV + yi0, o11 = xi1*FZV + yi1;
            const float* p = img_feats + (size_t)b * (CCH*FXV*FZV);
            #pragma unroll
            for (int c = 0; c < CCH; c++) {
                const float* pc = p + c * (FXV*FZV);
                fsum[c] += w00*pc[o00] + w01*pc[o01] + w10*pc[o10] + w11*pc[o11];
            }
        }

        // ---- variance & render_depth bilinear on swapped [W=400 (h), H=224 (w)] ----
        // x (width, H=224) from v; y (height, W=400) from u
        {
            float xf = v - 0.5f;
            float yf = u - 0.5f;
            float x0f = floorf(xf), y0f = floorf(yf);
            float wx = xf - x0f, wy = yf - y0f;
            int x0 = (int)x0f, y0 = (int)y0f;
            float vx0 = (x0   >= 0 && x0   < IMG_H) ? 1.0f : 0.0f;
            float vx1 = (x0+1 >= 0 && x0+1 < IMG_H) ? 1.0f : 0.0f;
            float vy0 = (y0   >= 0 && y0   < IMG_W) ? 1.0f : 0.0f;
            float vy1 = (y0+1 >= 0 && y0+1 < IMG_W) ? 1.0f : 0.0f;
            float w00 = (1.0f-wx)*(1.0f-wy)*vx0*vy0;
            float w10 = wx*(1.0f-wy)*vx1*vy0;
            float w01 = (1.0f-wx)*wy*vx0*vy1;
            float w11 = wx*wy*vx1*vy1;
            int xi0 = min(max(x0,   0), IMG_H-1), xi1 = min(max(x0+1, 0), IMG_H-1);
            int yi0 = min(max(y0,   0), IMG_W-1), yi1 = min(max(y0+1, 0), IMG_W-1);
            // variances[b,0,xi,yi] -> offset xi*400 + yi
            int o00 = xi0*IMG_W + yi0, o01 = xi0*IMG_W + yi1;
            int o10 = xi1*IMG_W + yi0, o11 = xi1*IMG_W + yi1;
            const float* pv = variances    + (size_t)b * (IMG_H*IMG_W);
            const float* pd = render_depth + (size_t)b * (IMG_H*IMG_W);
            vsum  += w00*pv[o00] + w01*pv[o01] + w10*pv[o10] + w11*pv[o11];
            ndsum += w00*pd[o00] + w01*pd[o01] + w10*pd[o10] + w11*pd[o11];
        }
    }

    float invd = 1.0f / (wsum + 1e-6f);
    // out_feats: [B, C*Y, X, Z]; element ((c*Y+y)*X+x)*Z+z = c*NVOX + n
    #pragma unroll
    for (int c = 0; c < CCH; c++) out[(size_t)c * NVOX + n] = fsum[c] * invd;
    out[(size_t)CCH*NVOX + n]              = vsum  * invd;  // var_info
    out[(size_t)CCH*NVOX + NVOX + n]       = zsum  * invd;  // depth
    out[(size_t)CCH*NVOX + 2*(size_t)NVOX + n] = ndsum * invd;  // nerf_depth
}

extern "C" void kernel_launch(void* const* d_in, const int* in_sizes, int n_in,
                              void* d_out, int out_size, void* d_ws, size_t ws_size,
                              hipStream_t stream) {
    const float* img_feats    = (const float*)d_in[0];
    const float* variances    = (const float*)d_in[1];
    const float* render_depth = (const float*)d_in[2];
    const float* coords       = (const float*)d_in[3];
    const float* Ps           = (const float*)d_in[4];
    const float* Ks           = (const float*)d_in[5];
    float* out = (float*)d_out;

    dim3 grid(NVOX / 256);
    dim3 block(256);
    hipLaunchKernelGGL(mvmap_main, grid, block, 0, stream,
                       img_feats, variances, render_depth, coords, Ps, Ks, out);
}